// Round 5
// baseline (80.654 us; speedup 1.0000x reference)
//
#include <hip/hip_runtime.h>
#include <math.h>

#define EPSF 1e-8f
#define HW 36864
#define SHALF 4753           // 49*97 stored upper half per corr map

// ws float offsets
#define OFF_INV    0
#define OFF_NORM   48
#define OFF_MAX    144       // [0]=pred max bits, [1]=target max bits
#define OFF_ACC    146       // loss accumulator
#define OFF_CNT2   147       // post max-barrier counter
#define OFF_CNT3   148       // post finalize counter
#define OFF_PART   160       // 48*2 per-image sum/sumsq atomic partials
#define OFF_CTR    256       // 48 per-image arrival counters
#define OFF_PARTS  1024      // 768*4753 floats: per-(img,chunk) partial corr
#define OFF_PREP   3651328   // ushort region: 48*36864 centered-bf16 images

// autocorr geometry
#define CY 12                // y0 rows per block; 16 chunks/img; 768 blocks
#define AR 61                // staged A rows (rows >= CY+48 only feed discarded sy>48)
#define APITCH 400           // bytes per A row
#define CPB 720              // bytes per B parity copy (45 chunks x 16B)
#define RB 5824              // bytes per staged B row (8 padded copies)
#define ABYTES (AR*APITCH)   // 24400
#define BBYTES (4*RB)        // 23296 (4 rows, single buffer)
#define LDSB (ABYTES + BBYTES)
#define ESTR 272             // epilogue lane stride (68 dw = 4 mod 8 -> conflict-free b128)

typedef short short8 __attribute__((ext_vector_type(8)));
typedef float f32x4 __attribute__((ext_vector_type(4)));

__device__ __forceinline__ unsigned int pk2(float a, float b) {
  union { float f; unsigned int u; } x, y;
  x.f = a; y.f = b;
  unsigned int ra = x.u + 0x7fffu + ((x.u >> 16) & 1u);   // RNE to bf16
  unsigned int rb = y.u + 0x7fffu + ((y.u >> 16) & 1u);
  return (ra >> 16) | (rb & 0xffff0000u);
}

// ---------------- Kernel 1: fused stats + centered-bf16 prep ----------------
__global__ __launch_bounds__(256) void stats_prep(const float* __restrict__ pred,
                                                  const float* __restrict__ target,
                                                  float* __restrict__ ws) {
  int blk = blockIdx.x, tid = threadIdx.x;
  int img = blk >> 2, qtr = blk & 3;
  int t = img / 24, local = img % 24;
  const float* src = (t ? target : pred) + (size_t)local * HW + qtr * 9216;

  const float4* s4 = (const float4*)src;
  float s = 0.f, sq = 0.f;
  for (int i = tid; i < 2304; i += 256) {
    float4 v = s4[i];
    s  += (v.x + v.y) + (v.z + v.w);
    sq += (v.x*v.x + v.y*v.y) + (v.z*v.z + v.w*v.w);
  }
#pragma unroll
  for (int o = 32; o > 0; o >>= 1) { s += __shfl_down(s, o); sq += __shfl_down(sq, o); }
  __shared__ float rs[4], rq[4], bcast[1];
  int lane = tid & 63, wv = tid >> 6;
  if (!lane) { rs[wv] = s; rq[wv] = sq; }
  __syncthreads();
  if (!tid) {
    s  = (rs[0] + rs[1]) + (rs[2] + rs[3]);
    sq = (rq[0] + rq[1]) + (rq[2] + rq[3]);
    atomicAdd(&ws[OFF_PART + 2*img],     s);
    atomicAdd(&ws[OFF_PART + 2*img + 1], sq);
    __threadfence();
    atomicAdd((int*)ws + OFF_CTR + img, 1);
    while (atomicAdd((int*)ws + OFF_CTR + img, 0) < 4) { }
    float S1 = atomicAdd(&ws[OFF_PART + 2*img],     0.f);
    float Q  = atomicAdd(&ws[OFF_PART + 2*img + 1], 0.f);
    float mean = S1 / (float)HW;
    float M2 = fmaxf(Q - S1 * S1 / (float)HW, 0.f);
    float inv = 1.f / (sqrtf(M2 / (float)(HW - 1)) + EPSF);
    bcast[0] = mean;
    if (qtr == 0) {
      ws[OFF_INV  + img] = inv;
      ws[OFF_NORM + img] = sqrtf(M2) * inv;   // sqrt(sum xn^2)
    }
  }
  __syncthreads();
  float mean = bcast[0];
  unsigned short* prep = (unsigned short*)(ws + OFF_PREP) + (size_t)img * HW + qtr * 9216;
  for (int i = tid; i < 2304; i += 256) {
    float4 v = s4[i];
    uint2 d; d.x = pk2(v.x - mean, v.y - mean); d.y = pk2(v.z - mean, v.w - mean);
    *(uint2*)(prep + i * 4) = d;
  }
}

// ---------------- Kernel 2: autocorrelation via bf16 MFMA ----------------
// Block = (img, 12-row y0-chunk). Wave w = K-split (rows 4j+w); full mt=4 x nt=7 tile.
// No global atomics: block stores its partial tile to parts[img][chunk][49*97].
__global__ __launch_bounds__(256, 2) void autocorr_mfma(float* __restrict__ ws) {
  int blk = blockIdx.x;
  int img = blk >> 4, chunk = blk & 15;
  int Y = chunk * CY;
  const unsigned short* prep = (const unsigned short*)(ws + OFF_PREP) + (size_t)img * HW;
  float inv = ws[OFF_INV + img];
  float scale = inv * inv;

  __shared__ __align__(16) char lds[LDSB];
  char* Al = lds;
  char* Bl = lds + ABYTES;

  int tid = threadIdx.x;
  int w = tid >> 6, lane = tid & 63, c = lane & 15, h = lane >> 4;

  // ---- A stage: rows Y..Y+60 (zeros beyond image) ----
  int RV = 192 - Y;
  for (int m = tid; m < AR * 24; m += 256) {
    int r = m / 24, k = m - r * 24;
    short8 v = (short8)(short)0;
    if (r < RV) v = *(const short8*)(prep + (Y + r) * 192 + k * 8);
    *(short8*)(Al + r * APITCH + k * 16) = v;
  }

  // ---- B staging, async split: load(j) to regs early, write after barrier ----
  int srr = tid / 45, sk = tid - srr * 45;     // 180 staging threads
  unsigned short q[15];
  auto stage_load = [&](int jd) {
    if (tid < 180) {
      const unsigned short* srow = prep + (Y + 4 * jd + srr) * 192;
      int e0 = 8 * sk - 112;                   // P[E] = u[x = E-112]
#pragma unroll
      for (int i2 = 0; i2 < 15; i2++) {
        int x = e0 + i2;
        q[i2] = ((unsigned)x < 192u) ? srow[x] : (unsigned short)0;
      }
    }
  };
  auto stage_write = [&]() {
    if (tid < 180) {
      unsigned int D[8], Sh[7];
#pragma unroll
      for (int a2 = 0; a2 < 7; a2++) D[a2] = (unsigned)q[2*a2] | ((unsigned)q[2*a2+1] << 16);
      D[7] = (unsigned)q[14];
#pragma unroll
      for (int b2 = 0; b2 < 7; b2++) Sh[b2] = (D[b2] >> 16) | (D[b2+1] << 16);
      char* base = Bl + srr * RB + sk * 16;
#pragma unroll
      for (int p = 0; p < 8; p++) {
        int pb = (p == 0) ? 16 : ((p & 1) ? 80 : 32);
        int4 v;
        if ((p & 1) == 0) { v.x = (int)D[p/2]; v.y = (int)D[p/2+1]; v.z = (int)D[p/2+2]; v.w = (int)D[p/2+3]; }
        else { v.x = (int)Sh[(p-1)/2]; v.y = (int)Sh[(p-1)/2+1]; v.z = (int)Sh[(p-1)/2+2]; v.w = (int)Sh[(p-1)/2+3]; }
        *(int4*)(base + p * CPB + pb) = v;
      }
    }
  };

  // lane-constant B addressing: copy p = (-c) mod 8, pad-equalized
  int p_l = (8 - (c & 7)) & 7;
  int q_l = (c == 0) ? 0 : ((c <= 8) ? 1 : 2);
  int pad_l = (p_l == 0) ? 16 : ((p_l & 1) ? 80 : 32);
  int LB0 = p_l * CPB + pad_l + 16 * (h - q_l) + 128;   // window wi at LB0 + 32*wi

  f32x4 acc[4][7];
#pragma unroll
  for (int mt = 0; mt < 4; mt++)
#pragma unroll
    for (int nt = 0; nt < 7; nt++) acc[mt][nt] = (f32x4)0.f;

  stage_load(0);
  for (int j = 0; j < 3; ++j) {
    __syncthreads();                  // previous compute done reading B
    stage_write();                    // write row-set j (vmcnt waits inside)
    __syncthreads();                  // B ready
    if (j < 2) stage_load(j + 1);     // issue next loads; hide under compute

    const char* pB = Bl + w * RB + LB0;
    int rb[4];
#pragma unroll
    for (int mt = 0; mt < 4; mt++) {
      int ra = 4 * j + w + 16 * mt + c;
      rb[mt] = (ra > 60 ? 60 : ra) * APITCH + 16 * h;
    }
    short8 Wf[8];
#pragma unroll
    for (int wi = 0; wi < 7; wi++) Wf[wi] = *(const short8*)(pB + 32 * wi);
#pragma unroll
    for (int t = 0; t < 6; t++) {
      if (t < 5) Wf[(2*t+7) & 7] = *(const short8*)(pB + 32 * (2*t+7));
      short8 Af[4];
#pragma unroll
      for (int mt = 0; mt < 4; mt++) Af[mt] = *(const short8*)(Al + rb[mt] + 64 * t);
#pragma unroll
      for (int mt = 0; mt < 4; mt++)
#pragma unroll
        for (int nt = 0; nt < 7; nt++)
          acc[mt][nt] = __builtin_amdgcn_mfma_f32_16x16x32_bf16(Af[mt], Wf[(2*t+6-nt) & 7], acc[mt][nt], 0, 0, 0);
      if (t < 5) Wf[(2*t+8) & 7] = *(const short8*)(pB + 32 * (2*t+8));
    }
  }

  // ---- K-combine across waves via LDS, then plain partial stores ----
  __syncthreads();
  if (w >= 2) {
    char* rg = lds + (w - 2) * 17408 + lane * ESTR;
#pragma unroll
    for (int mt = 0; mt < 2; mt++)
#pragma unroll
      for (int nt = 0; nt < 7; nt++) *(f32x4*)(rg + (mt*7+nt)*16) = acc[mt][nt];
  }
  __syncthreads();
  if (w < 2) {
    const char* rg = lds + w * 17408 + lane * ESTR;
#pragma unroll
    for (int mt = 0; mt < 2; mt++)
#pragma unroll
      for (int nt = 0; nt < 7; nt++) {
        f32x4 o = *(const f32x4*)(rg + (mt*7+nt)*16);
        acc[mt][nt][0] += o[0]; acc[mt][nt][1] += o[1]; acc[mt][nt][2] += o[2]; acc[mt][nt][3] += o[3];
      }
  }
  __syncthreads();
  if (w >= 2) {
    char* rg = lds + (w - 2) * 17408 + lane * ESTR;
#pragma unroll
    for (int mt = 2; mt < 4; mt++)
#pragma unroll
      for (int nt = 0; nt < 7; nt++) *(f32x4*)(rg + ((mt-2)*7+nt)*16) = acc[mt][nt];
  }
  __syncthreads();
  if (w < 2) {
    const char* rg = lds + w * 17408 + lane * ESTR;
#pragma unroll
    for (int mt = 2; mt < 4; mt++)
#pragma unroll
      for (int nt = 0; nt < 7; nt++) {
        f32x4 o = *(const f32x4*)(rg + ((mt-2)*7+nt)*16);
        acc[mt][nt][0] += o[0]; acc[mt][nt][1] += o[1]; acc[mt][nt][2] += o[2]; acc[mt][nt][3] += o[3];
      }
  }
  __syncthreads();
  if (w == 1) {   // send acc[0..1] to w0's side
    char* rg = lds + lane * ESTR;
#pragma unroll
    for (int mt = 0; mt < 2; mt++)
#pragma unroll
      for (int nt = 0; nt < 7; nt++) *(f32x4*)(rg + (mt*7+nt)*16) = acc[mt][nt];
  }
  if (w == 0) {   // send acc[2..3] to w1's side
    char* rg = lds + 17408 + lane * ESTR;
#pragma unroll
    for (int mt = 2; mt < 4; mt++)
#pragma unroll
      for (int nt = 0; nt < 7; nt++) *(f32x4*)(rg + ((mt-2)*7+nt)*16) = acc[mt][nt];
  }
  __syncthreads();
  float* part = ws + OFF_PARTS + (size_t)(img * 16 + chunk) * SHALF;
  if (w == 0) {
    const char* rg = lds + lane * ESTR;
#pragma unroll
    for (int mt = 0; mt < 2; mt++)
#pragma unroll
      for (int nt = 0; nt < 7; nt++) {
        f32x4 o = *(const f32x4*)(rg + (mt*7+nt)*16);
        int s = 16 * nt + c;
        if (s <= 96)
#pragma unroll
          for (int r = 0; r < 4; r++) {
            int sy = 16 * mt + 4 * h + r;
            part[sy * 97 + s] = (acc[mt][nt][r] + o[r]) * scale;
          }
      }
  } else if (w == 1) {
    const char* rg = lds + 17408 + lane * ESTR;
#pragma unroll
    for (int mt = 2; mt < 4; mt++)
#pragma unroll
      for (int nt = 0; nt < 7; nt++) {
        f32x4 o = *(const f32x4*)(rg + ((mt-2)*7+nt)*16);
        int s = 16 * nt + c;
        if (s <= 96)
#pragma unroll
          for (int r = 0; r < 4; r++) {
            int sy = 32 + 16 * (mt - 2) + 4 * h + r;
            if (sy <= 48)
              part[sy * 97 + s] = (acc[mt][nt][r] + o[r]) * scale;
          }
      }
  }
}

// ---------------- Kernel 3: fused 16-way reduce + max + loss + finalize ----------------
// 256 blocks (all co-resident): block = (b = blk>>5, seg = blk&31), 149 offs/seg.
// Channel sums kept in registers across the device-wide max spin-barrier.
__global__ __launch_bounds__(256) void post_kernel(float* __restrict__ ws,
                                                   float* __restrict__ out) {
  __shared__ float wsh[48];
  __shared__ float shv[2];
  int tid = threadIdx.x;
  if (tid < 48) wsh[tid] = (1.f / 3.f) / (ws[OFF_NORM + tid] + EPSF);
  __syncthreads();
  int b = blockIdx.x >> 5, seg = blockIdx.x & 31;
  int off = seg * 149 + tid;
  bool act = (tid < 149) && (off < SHALF);
  float p0 = 0.f, p1 = 0.f, p2 = 0.f, q0 = 0.f, q1 = 0.f, q2 = 0.f;
  if (act) {
    const float* P = ws + OFF_PARTS;
    const float* pa = P + (size_t)((3*b + 0) * 16) * SHALF + off;
    const float* pb = P + (size_t)((3*b + 1) * 16) * SHALF + off;
    const float* pc = P + (size_t)((3*b + 2) * 16) * SHALF + off;
    const float* ta = P + (size_t)((24 + 3*b + 0) * 16) * SHALF + off;
    const float* tb = P + (size_t)((24 + 3*b + 1) * 16) * SHALF + off;
    const float* tc = P + (size_t)((24 + 3*b + 2) * 16) * SHALF + off;
#pragma unroll
    for (int ch = 0; ch < 16; ch++) {
      p0 += pa[ch * SHALF]; p1 += pb[ch * SHALF]; p2 += pc[ch * SHALF];
      q0 += ta[ch * SHALF]; q1 += tb[ch * SHALF]; q2 += tc[ch * SHALF];
    }
  }
  // ---- max phase ----
  float mp = 0.f, mt2 = 0.f;
#pragma unroll
  for (int i = 0; i < 8; i++) {
    float pv = p0 * wsh[i*3] + p1 * wsh[i*3+1] + p2 * wsh[i*3+2];
    float tv = q0 * wsh[24+i*3] + q1 * wsh[24+i*3+1] + q2 * wsh[24+i*3+2];
    mp = fmaxf(mp, pv); mt2 = fmaxf(mt2, tv);
  }
#pragma unroll
  for (int o = 32; o > 0; o >>= 1) { mp = fmaxf(mp, __shfl_down(mp, o)); mt2 = fmaxf(mt2, __shfl_down(mt2, o)); }
  __shared__ float rp[4], rt[4];
  int lane = tid & 63, wv = tid >> 6;
  if (!lane) { rp[wv] = mp; rt[wv] = mt2; }
  __syncthreads();
  if (!tid) {
    mp  = fmaxf(fmaxf(rp[0], rp[1]), fmaxf(rp[2], rp[3]));
    mt2 = fmaxf(fmaxf(rt[0], rt[1]), fmaxf(rt[2], rt[3]));
    atomicMax((int*)ws + OFF_MAX,     __float_as_int(mp));
    atomicMax((int*)ws + OFF_MAX + 1, __float_as_int(mt2));
    __threadfence();
    atomicAdd((int*)ws + OFF_CNT2, 1);
    while (atomicAdd((int*)ws + OFF_CNT2, 0) < 256) { }
    int mpb = atomicAdd((int*)ws + OFF_MAX, 0);
    int mtb = atomicAdd((int*)ws + OFF_MAX + 1, 0);
    shv[0] = 1.f / (__int_as_float(mpb) + EPSF);
    shv[1] = 1.f / (__int_as_float(mtb) + EPSF);
  }
  __syncthreads();
  float imp = shv[0], imt = shv[1];
  // ---- loss phase (recompute combos from registers) ----
  float acc = 0.f;
  if (act) {
    float a8 = 0.f;
#pragma unroll
    for (int i = 0; i < 8; i++) {
      float pv = (p0 * wsh[i*3] + p1 * wsh[i*3+1] + p2 * wsh[i*3+2]) * imp;
      float tv = (q0 * wsh[24+i*3] + q1 * wsh[24+i*3+1] + q2 * wsh[24+i*3+2]) * imt;
      a8 += fabsf(pv - tv);
    }
    acc = ((off < 97) ? 1.f : 2.f) * a8;   // sy=0 row once, others mirror x2
  }
#pragma unroll
  for (int o = 32; o > 0; o >>= 1) acc += __shfl_down(acc, o);
  __shared__ float r[4];
  if (!lane) r[wv] = acc;
  __syncthreads();
  if (!tid) {
    float bs = (r[0] + r[1]) + (r[2] + r[3]);
    atomicAdd(&ws[OFF_ACC], bs);
    __threadfence();
    int old = atomicAdd((int*)ws + OFF_CNT3, 1);
    if (old == 255) {
      float total = atomicAdd(&ws[OFF_ACC], 0.f);
      out[0] = total * (1.0f / 602176.0f);   // mean over 8*8*97*97
    }
  }
}

extern "C" void kernel_launch(void* const* d_in, const int* in_sizes, int n_in,
                              void* d_out, int out_size, void* d_ws, size_t ws_size,
                              hipStream_t stream) {
  const float* pred   = (const float*)d_in[0];
  const float* target = (const float*)d_in[1];
  float* ws  = (float*)d_ws;
  float* out = (float*)d_out;

  // zero scalars/counters: floats [144, 304)
  hipMemsetAsync((char*)d_ws + 144 * sizeof(float), 0, 160 * sizeof(float), stream);
  hipLaunchKernelGGL(stats_prep,    dim3(192),     dim3(256), 0, stream, pred, target, ws);
  hipLaunchKernelGGL(autocorr_mfma, dim3(48 * 16), dim3(256), 0, stream, ws);
  hipLaunchKernelGGL(post_kernel,   dim3(256),     dim3(256), 0, stream, ws, out);
}